// Round 5
// baseline (106.255 us; speedup 1.0000x reference)
//
#include <hip/hip_runtime.h>
#include <math.h>

#define EPSF 1e-7f

typedef __attribute__((ext_vector_type(4))) float f32x4;
typedef __attribute__((ext_vector_type(8))) short s16x8;

__device__ __forceinline__ unsigned short f2bf(float f) {
    unsigned u = __float_as_uint(f);
    u = (u + 0x7fffu + ((u >> 16) & 1u)) >> 16;
    return (unsigned short)u;
}
__device__ __forceinline__ float bf2f(unsigned short s) {
    return __uint_as_float(((unsigned)s) << 16);
}
__device__ __forceinline__ s16x8 cvt8(const float* p) {
    s16x8 r;
    #pragma unroll
    for (int i = 0; i < 8; ++i) r[i] = (short)f2bf(p[i]);
    return r;
}
__device__ __forceinline__ float wave_reduce_sum(float v) {
    #pragma unroll
    for (int o = 32; o > 0; o >>= 1) v += __shfl_xor(v, o, 64);
    return v;
}

// K1: qkv = diag(s_logmap) * (x @ W_qkv) + b.  A = x fp32 (cvt to bf16 in-reg),
// B = W fp32 [K][N] strided-gathered + cvt. Row-scale in LDS prologue.
// Grid 192 blocks x 256 thr; each wave one 32x32 C tile; nwc=48 (div by 4 -> wr
// uniform per block).
__global__ __launch_bounds__(256, 4) void k_qkv(
        const float* __restrict__ x, const float* __restrict__ W,
        const float* __restrict__ bias, const float* __restrict__ c_sphere,
        float* __restrict__ qkv) {
    const int K = 512, NN = 1536;
    __shared__ float part[32][8];
    __shared__ float sL[32];
    int tid = threadIdx.x;
    int wid0 = blockIdx.x * 4;
    int wr = wid0 / 48;                       // same for all 4 waves
    {   // prologue: ||x_row||^2 for the block's 32 rows
        int row = tid >> 3, seg = tid & 7;
        const float* xr = x + (size_t)(wr * 32 + row) * K + seg * 64;
        float ss = 0.f;
        #pragma unroll
        for (int i = 0; i < 16; ++i) {
            float4 v = *(const float4*)(xr + i * 4);
            ss += v.x * v.x + v.y * v.y + v.z * v.z + v.w * v.w;
        }
        part[row][seg] = ss;
    }
    __syncthreads();
    if (tid < 32) {
        float ss = 0.f;
        #pragma unroll
        for (int i = 0; i < 8; ++i) ss += part[tid][i];
        float c = c_sphere[0];
        float sqc = fmaxf(sqrtf(c), EPSF);
        float yn = sqrtf(ss);
        sL[tid] = (yn < EPSF) ? 0.f
                 : atanhf(fminf(yn, 1.f - EPSF)) / (sqc * fmaxf(yn, EPSF));
    }
    __syncthreads();
    int wv = tid >> 6, lane = tid & 63, l15 = lane & 15, kb = lane >> 4;
    int wc = (wid0 + wv) % 48;
    int col0 = wc * 32;
    const float* Ab = x + (size_t)(wr * 32 + l15) * K + kb * 8;
    f32x4 acc[2][2] = {};
    #pragma unroll 2
    for (int k0 = 0; k0 < K; k0 += 32) {
        s16x8 a0 = cvt8(Ab + k0);
        s16x8 a1 = cvt8(Ab + 16 * K + k0);
        s16x8 b0, b1;
        #pragma unroll
        for (int t = 0; t < 8; ++t) {
            const float* wp = W + (size_t)(k0 + kb * 8 + t) * NN + col0 + l15;
            b0[t] = (short)f2bf(wp[0]);
            b1[t] = (short)f2bf(wp[16]);
        }
        acc[0][0] = __builtin_amdgcn_mfma_f32_16x16x32_bf16(a0, b0, acc[0][0], 0, 0, 0);
        acc[0][1] = __builtin_amdgcn_mfma_f32_16x16x32_bf16(a0, b1, acc[0][1], 0, 0, 0);
        acc[1][0] = __builtin_amdgcn_mfma_f32_16x16x32_bf16(a1, b0, acc[1][0], 0, 0, 0);
        acc[1][1] = __builtin_amdgcn_mfma_f32_16x16x32_bf16(a1, b1, acc[1][1], 0, 0, 0);
    }
    #pragma unroll
    for (int mi = 0; mi < 2; ++mi)
        #pragma unroll
        for (int r = 0; r < 4; ++r) {
            int row_l = mi * 16 + kb * 4 + r;
            int row = wr * 32 + row_l;
            float sc = sL[row_l];
            #pragma unroll
            for (int ni = 0; ni < 2; ++ni) {
                int col = col0 + ni * 16 + l15;
                qkv[(size_t)row * NN + col] = acc[mi][ni][r] * sc + bias[col];
            }
        }
}

// K2: RoPE on q,k; expmap0; relayouts. One wave per (h,n) vector.
__global__ void k_rope_expmap(const float* __restrict__ qkv, const float* __restrict__ freqs,
                              const float* __restrict__ c_logits,
                              unsigned short* __restrict__ qh, unsigned short* __restrict__ kh,
                              unsigned short* __restrict__ vt,
                              float* __restrict__ x2q, float* __restrict__ y2k) {
    const int N = 512;
    int wave = threadIdx.x >> 6, lane = threadIdx.x & 63;
    int vec = blockIdx.x * 4 + wave;     // vec = h*N + n
    int h = vec >> 9;
    int n = vec & 511;
    float c = log1pf(expf(c_logits[h]));
    float sqc = fmaxf(sqrtf(c), EPSF);
    int j = lane & 31;
    float f = freqs[n * 32 + j];
    float cs = cosf(f), sn = sinf(f);
    const float* base = qkv + (size_t)n * 1536;
    size_t oidx = ((size_t)h * N + n) * 64 + lane;
    {
        float qa = base[h * 64 + lane];
        float qb = base[h * 64 + (lane ^ 32)];
        float qr = (lane < 32) ? (qa * cs - qb * sn) : (qa * cs + qb * sn);
        float vn2 = wave_reduce_sum(qr * qr);
        float vn = sqrtf(vn2);
        float scale, fn;
        if (vn < EPSF) { scale = 0.f; fn = 0.f; }
        else {
            float mag = tanhf(sqc * vn) / sqc;
            scale = mag / fmaxf(vn, EPSF);
            fn = mag;
            if (fn >= 1.f) { scale *= (1.f - EPSF) / fn; fn = 1.f - EPSF; }
        }
        qh[oidx] = f2bf(qr * scale);
        if (lane == 0) x2q[h * N + n] = fn * fn;
    }
    {
        float ka = base[512 + h * 64 + lane];
        float kb = base[512 + h * 64 + (lane ^ 32)];
        float kr = (lane < 32) ? (ka * cs - kb * sn) : (ka * cs + kb * sn);
        float vn2 = wave_reduce_sum(kr * kr);
        float vn = sqrtf(vn2);
        float scale, fn;
        if (vn < EPSF) { scale = 0.f; fn = 0.f; }
        else {
            float mag = tanhf(sqc * vn) / sqc;
            scale = mag / fmaxf(vn, EPSF);
            fn = mag;
            if (fn >= 1.f) { scale *= (1.f - EPSF) / fn; fn = 1.f - EPSF; }
        }
        kh[oidx] = f2bf(kr * scale);
        if (lane == 0) y2k[h * N + n] = fn * fn;
    }
    vt[((size_t)h * 64 + lane) * N + n] = f2bf(base[1024 + h * 64 + lane]);
}

// K3: fused attention. Block = (h, 64-q-row tile), 4 waves 2x2.
// Per kt<=qt: S quadrants (MFMA) -> dist/exp epilogue + shfl row-sums ->
// P tile to LDS (bf16) -> PV MFMA accumulating O. Normalize once at end.
// No max pass needed: scores <= 0 so exp in (0,1].
__global__ __launch_bounds__(256, 2) void k_attn(
        const unsigned short* __restrict__ qh, const unsigned short* __restrict__ kh,
        const unsigned short* __restrict__ vt,
        const float* __restrict__ x2q, const float* __restrict__ y2k,
        const float* __restrict__ c_logits, const float* __restrict__ geo_scale,
        unsigned short* __restrict__ aout) {
    const int N = 512;
    int qt = blockIdx.x, h = blockIdx.y;
    int tid = threadIdx.x, lane = tid & 63, wv = tid >> 6;
    int wr = wv >> 1, wc = wv & 1, l15 = lane & 15, kb = lane >> 4;
    __shared__ __align__(16) unsigned short Pt[64][72];   // +8 shorts pad: 144B stride
    __shared__ float rs_part[2][2][32];
    __shared__ float inv_row[64];
    float c = log1pf(expf(c_logits[h]));
    float sqc = fmaxf(sqrtf(c), EPSF);
    float gs = geo_scale[h];
    int r0 = qt * 64;
    // persistent Q fragments (rows wr*32 + l15 / +16, full K=64)
    s16x8 qf[2][2];
    #pragma unroll
    for (int mi = 0; mi < 2; ++mi)
        #pragma unroll
        for (int ks = 0; ks < 2; ++ks)
            qf[mi][ks] = *(const s16x8*)(
                qh + ((size_t)(h * N + r0 + wr * 32 + mi * 16 + l15)) * 64 + ks * 32 + kb * 8);
    float x2r[2][4], bvr[2][4];
    #pragma unroll
    for (int mi = 0; mi < 2; ++mi)
        #pragma unroll
        for (int r = 0; r < 4; ++r) {
            float x2 = x2q[h * N + r0 + wr * 32 + mi * 16 + kb * 4 + r];
            x2r[mi][r] = x2;
            bvr[mi][r] = 1.f - c * x2;
        }
    float rs_acc[2][4] = {};
    f32x4 acc_o[2][2] = {};
    for (int kt = 0; kt <= qt; ++kt) {
        // ---- S = Q K^T quadrant ----
        f32x4 s[2][2] = {};
        const unsigned short* Kb = kh + ((size_t)(h * N + kt * 64 + wc * 32 + l15)) * 64 + kb * 8;
        #pragma unroll
        for (int ks = 0; ks < 2; ++ks) {
            s16x8 b0 = *(const s16x8*)(Kb + ks * 32);
            s16x8 b1 = *(const s16x8*)(Kb + 16 * 64 + ks * 32);
            s[0][0] = __builtin_amdgcn_mfma_f32_16x16x32_bf16(qf[0][ks], b0, s[0][0], 0, 0, 0);
            s[0][1] = __builtin_amdgcn_mfma_f32_16x16x32_bf16(qf[0][ks], b1, s[0][1], 0, 0, 0);
            s[1][0] = __builtin_amdgcn_mfma_f32_16x16x32_bf16(qf[1][ks], b0, s[1][0], 0, 0, 0);
            s[1][1] = __builtin_amdgcn_mfma_f32_16x16x32_bf16(qf[1][ks], b1, s[1][1], 0, 0, 0);
        }
        __syncthreads();   // previous iter's PV reads of Pt complete
        // ---- dist/exp epilogue + row-sum partials; write P to LDS ----
        bool diag = (kt == qt);
        #pragma unroll
        for (int mi = 0; mi < 2; ++mi)
            #pragma unroll
            for (int r = 0; r < 4; ++r) {
                int qi_l = wr * 32 + mi * 16 + kb * 4 + r;
                int qi = r0 + qi_l;
                float x2 = x2r[mi][r], b_ = bvr[mi][r];
                float prsum = 0.f;
                #pragma unroll
                for (int ni = 0; ni < 2; ++ni) {
                    int ki = kt * 64 + wc * 32 + ni * 16 + l15;
                    float y2 = y2k[h * N + ki];
                    float dot = s[mi][ni][r];
                    float a_ = 1.f + c * (y2 - 2.f * dot);
                    float num2 = a_ * a_ * x2 + b_ * b_ * y2 - 2.f * a_ * b_ * dot;
                    float den = fmaxf(1.f - 2.f * c * dot + c * c * x2 * y2, EPSF);
                    float nrm = sqrtf(fmaxf(num2, 0.f)) / den;
                    if (nrm >= 1.f) nrm = 1.f - EPSF;
                    float arg = fminf(sqc * nrm, 1.f - EPSF);
                    float sv = -gs * (2.f * atanhf(arg) / sqc);
                    float pe = (!diag || ki <= qi) ? expf(sv) : 0.f;
                    prsum += pe;
                    Pt[qi_l][wc * 32 + ni * 16 + l15] = f2bf(pe);
                }
                #pragma unroll
                for (int o = 1; o < 16; o <<= 1) prsum += __shfl_xor(prsum, o, 64);
                rs_acc[mi][r] += prsum;
            }
        __syncthreads();
        // ---- PV: O += P_tile @ V_tile ----
        const unsigned short* Vb = vt + ((size_t)(h * 64 + wc * 32 + l15)) * N + kt * 64 + kb * 8;
        #pragma unroll
        for (int ks = 0; ks < 2; ++ks) {
            s16x8 a0 = *(const s16x8*)(&Pt[wr * 32 + l15][ks * 32 + kb * 8]);
            s16x8 a1 = *(const s16x8*)(&Pt[wr * 32 + 16 + l15][ks * 32 + kb * 8]);
            s16x8 b0 = *(const s16x8*)(Vb + ks * 32);
            s16x8 b1 = *(const s16x8*)(Vb + (size_t)16 * N + ks * 32);
            acc_o[0][0] = __builtin_amdgcn_mfma_f32_16x16x32_bf16(a0, b0, acc_o[0][0], 0, 0, 0);
            acc_o[0][1] = __builtin_amdgcn_mfma_f32_16x16x32_bf16(a0, b1, acc_o[0][1], 0, 0, 0);
            acc_o[1][0] = __builtin_amdgcn_mfma_f32_16x16x32_bf16(a1, b0, acc_o[1][0], 0, 0, 0);
            acc_o[1][1] = __builtin_amdgcn_mfma_f32_16x16x32_bf16(a1, b1, acc_o[1][1], 0, 0, 0);
        }
    }
    // ---- combine row sums across wc, normalize, store ----
    if (l15 == 0) {
        #pragma unroll
        for (int mi = 0; mi < 2; ++mi)
            #pragma unroll
            for (int r = 0; r < 4; ++r)
                rs_part[wr][wc][mi * 16 + kb * 4 + r] = rs_acc[mi][r];
    }
    __syncthreads();
    if (tid < 64)
        inv_row[tid] = 1.f / (rs_part[tid >> 5][0][tid & 31] + rs_part[tid >> 5][1][tid & 31]);
    __syncthreads();
    #pragma unroll
    for (int mi = 0; mi < 2; ++mi)
        #pragma unroll
        for (int r = 0; r < 4; ++r) {
            int qi_l = wr * 32 + mi * 16 + kb * 4 + r;
            float il = inv_row[qi_l];
            int qi = r0 + qi_l;
            #pragma unroll
            for (int ni = 0; ni < 2; ++ni) {
                int d = wc * 32 + ni * 16 + l15;
                aout[(size_t)qi * 512 + h * 64 + d] = f2bf(acc_o[mi][ni][r] * il);
            }
        }
}

// K4: out = aout(bf16) @ W_out + b.  B strided-gathered fp32->bf16. nwc=16.
__global__ __launch_bounds__(256, 4) void k_out(
        const unsigned short* __restrict__ A, const float* __restrict__ W,
        const float* __restrict__ bias, float* __restrict__ C) {
    const int K = 512, NN = 512;
    int tid = threadIdx.x;
    int wv = tid >> 6, lane = tid & 63, l15 = lane & 15, kb = lane >> 4;
    int wid = blockIdx.x * 4 + wv;
    int wr = wid / 16, wc = wid % 16;
    int col0 = wc * 32;
    const unsigned short* Ab = A + (size_t)(wr * 32 + l15) * K + kb * 8;
    f32x4 acc[2][2] = {};
    #pragma unroll 2
    for (int k0 = 0; k0 < K; k0 += 32) {
        s16x8 a0 = *(const s16x8*)(Ab + k0);
        s16x8 a1 = *(const s16x8*)(Ab + 16 * K + k0);
        s16x8 b0, b1;
        #pragma unroll
        for (int t = 0; t < 8; ++t) {
            const float* wp = W + (size_t)(k0 + kb * 8 + t) * NN + col0 + l15;
            b0[t] = (short)f2bf(wp[0]);
            b1[t] = (short)f2bf(wp[16]);
        }
        acc[0][0] = __builtin_amdgcn_mfma_f32_16x16x32_bf16(a0, b0, acc[0][0], 0, 0, 0);
        acc[0][1] = __builtin_amdgcn_mfma_f32_16x16x32_bf16(a0, b1, acc[0][1], 0, 0, 0);
        acc[1][0] = __builtin_amdgcn_mfma_f32_16x16x32_bf16(a1, b0, acc[1][0], 0, 0, 0);
        acc[1][1] = __builtin_amdgcn_mfma_f32_16x16x32_bf16(a1, b1, acc[1][1], 0, 0, 0);
    }
    #pragma unroll
    for (int mi = 0; mi < 2; ++mi)
        #pragma unroll
        for (int r = 0; r < 4; ++r) {
            int row = wr * 32 + mi * 16 + kb * 4 + r;
            #pragma unroll
            for (int ni = 0; ni < 2; ++ni) {
                int col = col0 + ni * 16 + l15;
                C[(size_t)row * NN + col] = acc[mi][ni][r] + bias[col];
            }
        }
}

extern "C" void kernel_launch(void* const* d_in, const int* in_sizes, int n_in,
                              void* d_out, int out_size, void* d_ws, size_t ws_size,
                              hipStream_t stream) {
    const float* x_hyp     = (const float*)d_in[0];
    const float* freqs     = (const float*)d_in[1];
    const float* c_sphere  = (const float*)d_in[2];
    const float* w_qkv     = (const float*)d_in[3];
    const float* b_qkv     = (const float*)d_in[4];
    const float* w_out     = (const float*)d_in[5];
    const float* b_out     = (const float*)d_in[6];
    const float* c_logits  = (const float*)d_in[7];
    const float* geo_scale = (const float*)d_in[8];
    float* out = (float*)d_out;

    const int N = 512, H = 8;
    char* base = (char*)d_ws;
    float*          qkv    = (float*)base;             base += 3 * 1024 * 1024;
    unsigned short* qh16   = (unsigned short*)base;    base += 512 * 1024;
    unsigned short* kh16   = (unsigned short*)base;    base += 512 * 1024;
    unsigned short* vt16   = (unsigned short*)base;    base += 512 * 1024;
    unsigned short* aout16 = (unsigned short*)base;    base += 512 * 1024;
    float*          x2q    = (float*)base;             base += 16 * 1024;
    float*          y2k    = (float*)base;             base += 16 * 1024;

    k_qkv<<<192, 256, 0, stream>>>(x_hyp, w_qkv, b_qkv, c_sphere, qkv);
    k_rope_expmap<<<(H * N) / 4, 256, 0, stream>>>(qkv, freqs, c_logits,
                                                   qh16, kh16, vt16, x2q, y2k);
    k_attn<<<dim3(8, H), 256, 0, stream>>>(qh16, kh16, vt16, x2q, y2k,
                                           c_logits, geo_scale, aout16);
    k_out<<<64, 256, 0, stream>>>(aout16, w_out, b_out, out);
}

// Round 6
// 64.999 us; speedup vs baseline: 1.6347x; 1.6347x over previous
//
#include <hip/hip_runtime.h>
#include <math.h>

#define EPSF 1e-7f

typedef __attribute__((ext_vector_type(4))) float f32x4;
typedef __attribute__((ext_vector_type(8))) short s16x8;

__device__ __forceinline__ unsigned short f2bf(float f) {
    unsigned u = __float_as_uint(f);
    u = (u + 0x7fffu + ((u >> 16) & 1u)) >> 16;
    return (unsigned short)u;
}
__device__ __forceinline__ float bf2f(unsigned short s) {
    return __uint_as_float(((unsigned)s) << 16);
}
__device__ __forceinline__ s16x8 cvt8(const float* p) {
    s16x8 r;
    #pragma unroll
    for (int i = 0; i < 8; ++i) r[i] = (short)f2bf(p[i]);
    return r;
}
__device__ __forceinline__ float wave_reduce_sum(float v) {
    #pragma unroll
    for (int o = 32; o > 0; o >>= 1) v += __shfl_xor(v, o, 64);
    return v;
}

// K1: qkv = diag(s_logmap) * (x @ W_qkv) + b. A = x fp32 cvt in-reg,
// B = W fp32 [K][N] strided-gathered + cvt. Row-scale via LDS prologue.
__global__ __launch_bounds__(256, 4) void k_qkv(
        const float* __restrict__ x, const float* __restrict__ W,
        const float* __restrict__ bias, const float* __restrict__ c_sphere,
        float* __restrict__ qkv) {
    const int K = 512, NN = 1536;
    __shared__ float part[32][8];
    __shared__ float sL[32];
    int tid = threadIdx.x;
    int wid0 = blockIdx.x * 4;
    int wr = wid0 / 48;                       // same for all 4 waves
    {   // prologue: ||x_row||^2 for the block's 32 rows
        int row = tid >> 3, seg = tid & 7;
        const float* xr = x + (size_t)(wr * 32 + row) * K + seg * 64;
        float ss = 0.f;
        #pragma unroll
        for (int i = 0; i < 16; ++i) {
            float4 v = *(const float4*)(xr + i * 4);
            ss += v.x * v.x + v.y * v.y + v.z * v.z + v.w * v.w;
        }
        part[row][seg] = ss;
    }
    __syncthreads();
    if (tid < 32) {
        float ss = 0.f;
        #pragma unroll
        for (int i = 0; i < 8; ++i) ss += part[tid][i];
        float c = c_sphere[0];
        float sqc = fmaxf(sqrtf(c), EPSF);
        float yn = sqrtf(ss);
        sL[tid] = (yn < EPSF) ? 0.f
                 : atanhf(fminf(yn, 1.f - EPSF)) / (sqc * fmaxf(yn, EPSF));
    }
    __syncthreads();
    int wv = tid >> 6, lane = tid & 63, l15 = lane & 15, kb = lane >> 4;
    int wc = (wid0 + wv) % 48;
    int col0 = wc * 32;
    const float* Ab = x + (size_t)(wr * 32 + l15) * K + kb * 8;
    f32x4 acc[2][2] = {};
    #pragma unroll 2
    for (int k0 = 0; k0 < K; k0 += 32) {
        s16x8 a0 = cvt8(Ab + k0);
        s16x8 a1 = cvt8(Ab + 16 * K + k0);
        s16x8 b0, b1;
        #pragma unroll
        for (int t = 0; t < 8; ++t) {
            const float* wp = W + (size_t)(k0 + kb * 8 + t) * NN + col0 + l15;
            b0[t] = (short)f2bf(wp[0]);
            b1[t] = (short)f2bf(wp[16]);
        }
        acc[0][0] = __builtin_amdgcn_mfma_f32_16x16x32_bf16(a0, b0, acc[0][0], 0, 0, 0);
        acc[0][1] = __builtin_amdgcn_mfma_f32_16x16x32_bf16(a0, b1, acc[0][1], 0, 0, 0);
        acc[1][0] = __builtin_amdgcn_mfma_f32_16x16x32_bf16(a1, b0, acc[1][0], 0, 0, 0);
        acc[1][1] = __builtin_amdgcn_mfma_f32_16x16x32_bf16(a1, b1, acc[1][1], 0, 0, 0);
    }
    #pragma unroll
    for (int mi = 0; mi < 2; ++mi)
        #pragma unroll
        for (int r = 0; r < 4; ++r) {
            int row_l = mi * 16 + kb * 4 + r;
            int row = wr * 32 + row_l;
            float sc = sL[row_l];
            #pragma unroll
            for (int ni = 0; ni < 2; ++ni) {
                int col = col0 + ni * 16 + l15;
                qkv[(size_t)row * NN + col] = acc[mi][ni][r] * sc + bias[col];
            }
        }
}

// K2: RoPE on q,k; expmap0; relayouts. One wave per (h,n) vector.
__global__ void k_rope_expmap(const float* __restrict__ qkv, const float* __restrict__ freqs,
                              const float* __restrict__ c_logits,
                              unsigned short* __restrict__ qh, unsigned short* __restrict__ kh,
                              unsigned short* __restrict__ vt,
                              float* __restrict__ x2q, float* __restrict__ y2k) {
    const int N = 512;
    int wave = threadIdx.x >> 6, lane = threadIdx.x & 63;
    int vec = blockIdx.x * 4 + wave;     // vec = h*N + n
    int h = vec >> 9;
    int n = vec & 511;
    float c = log1pf(expf(c_logits[h]));
    float sqc = fmaxf(sqrtf(c), EPSF);
    int j = lane & 31;
    float f = freqs[n * 32 + j];
    float cs = cosf(f), sn = sinf(f);
    const float* base = qkv + (size_t)n * 1536;
    size_t oidx = ((size_t)h * N + n) * 64 + lane;
    {
        float qa = base[h * 64 + lane];
        float qb = base[h * 64 + (lane ^ 32)];
        float qr = (lane < 32) ? (qa * cs - qb * sn) : (qa * cs + qb * sn);
        float vn2 = wave_reduce_sum(qr * qr);
        float vn = sqrtf(vn2);
        float scale, fn;
        if (vn < EPSF) { scale = 0.f; fn = 0.f; }
        else {
            float mag = tanhf(sqc * vn) / sqc;
            scale = mag / fmaxf(vn, EPSF);
            fn = mag;
            if (fn >= 1.f) { scale *= (1.f - EPSF) / fn; fn = 1.f - EPSF; }
        }
        qh[oidx] = f2bf(qr * scale);
        if (lane == 0) x2q[h * N + n] = fn * fn;
    }
    {
        float ka = base[512 + h * 64 + lane];
        float kb = base[512 + h * 64 + (lane ^ 32)];
        float kr = (lane < 32) ? (ka * cs - kb * sn) : (ka * cs + kb * sn);
        float vn2 = wave_reduce_sum(kr * kr);
        float vn = sqrtf(vn2);
        float scale, fn;
        if (vn < EPSF) { scale = 0.f; fn = 0.f; }
        else {
            float mag = tanhf(sqc * vn) / sqc;
            scale = mag / fmaxf(vn, EPSF);
            fn = mag;
            if (fn >= 1.f) { scale *= (1.f - EPSF) / fn; fn = 1.f - EPSF; }
        }
        kh[oidx] = f2bf(kr * scale);
        if (lane == 0) y2k[h * N + n] = fn * fn;
    }
    vt[((size_t)h * 64 + lane) * N + n] = f2bf(base[1024 + h * 64 + lane]);
}

// K3: QK^T via MFMA per lower-triangular (h, 64x64 tile); epilogue computes
// hyperbolic dist + causal mask + exp -> P(bf16). 288 blocks: the
// transcendental epilogue runs on 73K threads in parallel.
__global__ __launch_bounds__(256, 4) void k_qkt_mfma(
        const unsigned short* __restrict__ qh, const unsigned short* __restrict__ kh,
        const float* __restrict__ x2q, const float* __restrict__ y2k,
        const float* __restrict__ c_logits, const float* __restrict__ geo_scale,
        unsigned short* __restrict__ P) {
    const int N = 512;
    int p = blockIdx.x, h = blockIdx.y;
    int qt = 0;
    while ((qt + 1) * (qt + 2) / 2 <= p) qt++;
    int kt = p - qt * (qt + 1) / 2;
    int tid = threadIdx.x, lane = tid & 63, wv = tid >> 6;
    int wr = wv >> 1, wc = wv & 1;
    int l15 = lane & 15, kb = lane >> 4;
    int qrow0 = qt * 64 + wr * 32, kcol0 = kt * 64 + wc * 32;
    const unsigned short* qb = qh + ((size_t)h * N + qrow0 + l15) * 64 + kb * 8;
    const unsigned short* kb_ = kh + ((size_t)h * N + kcol0 + l15) * 64 + kb * 8;
    f32x4 acc[2][2] = {};
    #pragma unroll
    for (int kk = 0; kk < 2; ++kk) {
        s16x8 a0 = *(const s16x8*)(qb + kk * 32);
        s16x8 a1 = *(const s16x8*)(qb + 16 * 64 + kk * 32);
        s16x8 b0 = *(const s16x8*)(kb_ + kk * 32);
        s16x8 b1 = *(const s16x8*)(kb_ + 16 * 64 + kk * 32);
        acc[0][0] = __builtin_amdgcn_mfma_f32_16x16x32_bf16(a0, b0, acc[0][0], 0, 0, 0);
        acc[0][1] = __builtin_amdgcn_mfma_f32_16x16x32_bf16(a0, b1, acc[0][1], 0, 0, 0);
        acc[1][0] = __builtin_amdgcn_mfma_f32_16x16x32_bf16(a1, b0, acc[1][0], 0, 0, 0);
        acc[1][1] = __builtin_amdgcn_mfma_f32_16x16x32_bf16(a1, b1, acc[1][1], 0, 0, 0);
    }
    float c = log1pf(expf(c_logits[h]));
    float sqc = fmaxf(sqrtf(c), EPSF);
    float gs = geo_scale[h];
    #pragma unroll
    for (int mi = 0; mi < 2; ++mi)
        #pragma unroll
        for (int r = 0; r < 4; ++r) {
            int qi = qrow0 + mi * 16 + kb * 4 + r;
            float x2 = x2q[h * N + qi];
            float b_ = 1.f - c * x2;
            #pragma unroll
            for (int ni = 0; ni < 2; ++ni) {
                int ki = kcol0 + ni * 16 + l15;
                float y2 = y2k[h * N + ki];
                float dot = acc[mi][ni][r];
                float a_ = 1.f + c * (y2 - 2.f * dot);
                float num2 = a_ * a_ * x2 + b_ * b_ * y2 - 2.f * a_ * b_ * dot;
                float den = fmaxf(1.f - 2.f * c * dot + c * c * x2 * y2, EPSF);
                float nrm = sqrtf(fmaxf(num2, 0.f)) / den;
                if (nrm >= 1.f) nrm = 1.f - EPSF;
                float arg = fminf(sqc * nrm, 1.f - EPSF);
                float s = -gs * (2.f * atanhf(arg) / sqc);
                float pe = (ki <= qi) ? expf(s) : 0.f;
                P[((size_t)(h * N + qi)) * N + ki] = f2bf(pe);
            }
        }
}

// K4: O = P @ V via MFMA with FUSED row-sum: each wave reads every causal P
// element of its rows exactly once in its A-fragments, so summing fragments
// in-register + shfl_xor(16,32) over the kb lane-groups gives the exact
// softmax denominator (P is zero above the diagonal). One LDS exchange
// rearranges sums from (mi,l15) layout to the C (mi,kb*4+r) layout.
__global__ __launch_bounds__(256, 4) void k_pv_mfma(
        const unsigned short* __restrict__ P, const unsigned short* __restrict__ vt,
        unsigned short* __restrict__ aout) {
    const int N = 512;
    int qt = blockIdx.x, h = blockIdx.y;
    int tid = threadIdx.x, lane = tid & 63, wv = tid >> 6;
    int wr = wv >> 1, wc = wv & 1;
    int l15 = lane & 15, kb = lane >> 4;
    int r0 = qt * 64 + wr * 32;
    int d0 = wc * 32;
    __shared__ float sums[64];
    const unsigned short* Pb = P + ((size_t)(h * N + r0 + l15)) * N + kb * 8;
    const unsigned short* Vb = vt + ((size_t)(h * 64 + d0 + l15)) * N + kb * 8;
    f32x4 acc[2][2] = {};
    float sa0 = 0.f, sa1 = 0.f;
    int kend = r0 + 32;    // causal coverage for rows r0..r0+31
    for (int k0 = 0; k0 < kend; k0 += 32) {
        s16x8 a0 = *(const s16x8*)(Pb + k0);
        s16x8 a1 = *(const s16x8*)(Pb + (size_t)16 * N + k0);
        s16x8 b0 = *(const s16x8*)(Vb + k0);
        s16x8 b1 = *(const s16x8*)(Vb + (size_t)16 * N + k0);
        #pragma unroll
        for (int t = 0; t < 8; ++t) {
            sa0 += bf2f((unsigned short)a0[t]);
            sa1 += bf2f((unsigned short)a1[t]);
        }
        acc[0][0] = __builtin_amdgcn_mfma_f32_16x16x32_bf16(a0, b0, acc[0][0], 0, 0, 0);
        acc[0][1] = __builtin_amdgcn_mfma_f32_16x16x32_bf16(a0, b1, acc[0][1], 0, 0, 0);
        acc[1][0] = __builtin_amdgcn_mfma_f32_16x16x32_bf16(a1, b0, acc[1][0], 0, 0, 0);
        acc[1][1] = __builtin_amdgcn_mfma_f32_16x16x32_bf16(a1, b1, acc[1][1], 0, 0, 0);
    }
    // reduce partial row-sums across the 4 kb groups (lanes l15+16k)
    sa0 += __shfl_xor(sa0, 16, 64); sa0 += __shfl_xor(sa0, 32, 64);
    sa1 += __shfl_xor(sa1, 16, 64); sa1 += __shfl_xor(sa1, 32, 64);
    if (wc == 0 && kb == 0) {
        sums[wr * 32 + l15] = sa0;
        sums[wr * 32 + 16 + l15] = sa1;
    }
    __syncthreads();
    #pragma unroll
    for (int mi = 0; mi < 2; ++mi)
        #pragma unroll
        for (int r = 0; r < 4; ++r) {
            int row_l = wr * 32 + mi * 16 + kb * 4 + r;
            int qi = qt * 64 + row_l;
            float il = 1.f / sums[row_l];
            #pragma unroll
            for (int ni = 0; ni < 2; ++ni) {
                int d = d0 + ni * 16 + l15;
                aout[(size_t)qi * 512 + h * 64 + d] = f2bf(acc[mi][ni][r] * il);
            }
        }
}

// K5: out = aout(bf16) @ W_out + b. B strided-gathered fp32->bf16.
__global__ __launch_bounds__(256, 4) void k_out(
        const unsigned short* __restrict__ A, const float* __restrict__ W,
        const float* __restrict__ bias, float* __restrict__ C) {
    const int K = 512, NN = 512;
    int tid = threadIdx.x;
    int wv = tid >> 6, lane = tid & 63, l15 = lane & 15, kb = lane >> 4;
    int wid = blockIdx.x * 4 + wv;
    int wr = wid / 16, wc = wid % 16;
    int col0 = wc * 32;
    const unsigned short* Ab = A + (size_t)(wr * 32 + l15) * K + kb * 8;
    f32x4 acc[2][2] = {};
    #pragma unroll 2
    for (int k0 = 0; k0 < K; k0 += 32) {
        s16x8 a0 = *(const s16x8*)(Ab + k0);
        s16x8 a1 = *(const s16x8*)(Ab + 16 * K + k0);
        s16x8 b0, b1;
        #pragma unroll
        for (int t = 0; t < 8; ++t) {
            const float* wp = W + (size_t)(k0 + kb * 8 + t) * NN + col0 + l15;
            b0[t] = (short)f2bf(wp[0]);
            b1[t] = (short)f2bf(wp[16]);
        }
        acc[0][0] = __builtin_amdgcn_mfma_f32_16x16x32_bf16(a0, b0, acc[0][0], 0, 0, 0);
        acc[0][1] = __builtin_amdgcn_mfma_f32_16x16x32_bf16(a0, b1, acc[0][1], 0, 0, 0);
        acc[1][0] = __builtin_amdgcn_mfma_f32_16x16x32_bf16(a1, b0, acc[1][0], 0, 0, 0);
        acc[1][1] = __builtin_amdgcn_mfma_f32_16x16x32_bf16(a1, b1, acc[1][1], 0, 0, 0);
    }
    #pragma unroll
    for (int mi = 0; mi < 2; ++mi)
        #pragma unroll
        for (int r = 0; r < 4; ++r) {
            int row = wr * 32 + mi * 16 + kb * 4 + r;
            #pragma unroll
            for (int ni = 0; ni < 2; ++ni) {
                int col = col0 + ni * 16 + l15;
                C[(size_t)row * NN + col] = acc[mi][ni][r] + bias[col];
            }
        }
}

extern "C" void kernel_launch(void* const* d_in, const int* in_sizes, int n_in,
                              void* d_out, int out_size, void* d_ws, size_t ws_size,
                              hipStream_t stream) {
    const float* x_hyp     = (const float*)d_in[0];
    const float* freqs     = (const float*)d_in[1];
    const float* c_sphere  = (const float*)d_in[2];
    const float* w_qkv     = (const float*)d_in[3];
    const float* b_qkv     = (const float*)d_in[4];
    const float* w_out     = (const float*)d_in[5];
    const float* b_out     = (const float*)d_in[6];
    const float* c_logits  = (const float*)d_in[7];
    const float* geo_scale = (const float*)d_in[8];
    float* out = (float*)d_out;

    const int N = 512, H = 8;
    char* base = (char*)d_ws;
    float*          qkv    = (float*)base;             base += 3 * 1024 * 1024;
    unsigned short* qh16   = (unsigned short*)base;    base += 512 * 1024;
    unsigned short* kh16   = (unsigned short*)base;    base += 512 * 1024;
    unsigned short* vt16   = (unsigned short*)base;    base += 512 * 1024;
    unsigned short* aout16 = (unsigned short*)base;    base += 512 * 1024;
    float*          x2q    = (float*)base;             base += 16 * 1024;
    float*          y2k    = (float*)base;             base += 16 * 1024;
    unsigned short* P16    = (unsigned short*)base;    base += 4 * 1024 * 1024;

    k_qkv<<<192, 256, 0, stream>>>(x_hyp, w_qkv, b_qkv, c_sphere, qkv);
    k_rope_expmap<<<(H * N) / 4, 256, 0, stream>>>(qkv, freqs, c_logits,
                                                   qh16, kh16, vt16, x2q, y2k);
    k_qkt_mfma<<<dim3(36, H), 256, 0, stream>>>(qh16, kh16, x2q, y2k,
                                                c_logits, geo_scale, P16);
    k_pv_mfma<<<dim3(8, H), 256, 0, stream>>>(P16, vt16, aout16);
    k_out<<<64, 256, 0, stream>>>(aout16, w_out, b_out, out);
}